// Round 7
// baseline (289.892 us; speedup 1.0000x reference)
//
#include <hip/hip_runtime.h>

#define BATCH 16
#define LQ    1024
#define LK    1024
#define DD    512

typedef unsigned int u32;
typedef short short8 __attribute__((ext_vector_type(8)));
typedef float f32x4 __attribute__((ext_vector_type(4)));
typedef u32 u32x2 __attribute__((ext_vector_type(2)));
typedef u32 u32x4 __attribute__((ext_vector_type(4)));
#define AS1 __attribute__((address_space(1)))
#define AS3 __attribute__((address_space(3)))

// ---------------------------------------------------------------------------
// split fp32 pair -> packed bf16 hi (truncation) and bf16 lo (= x - hi)
// ---------------------------------------------------------------------------
__device__ __forceinline__ void split2(float x0, float x1, u32& hp, u32& lp) {
    u32 u0 = __float_as_uint(x0), u1 = __float_as_uint(x1);
    hp = __builtin_amdgcn_perm(u1, u0, 0x07060302u);   // (bf16(x0), bf16(x1))
    float l0 = x0 - __uint_as_float(u0 & 0xffff0000u);
    float l1 = x1 - __uint_as_float(u1 & 0xffff0000u);
    lp = __builtin_amdgcn_perm(__float_as_uint(l1), __float_as_uint(l0), 0x07060302u);
}

__device__ __forceinline__ void mk_frags(f32x4 f0, f32x4 f1, short8& h, short8& l) {
    union { u32 u[4]; short8 s; } H, L;
    split2(f0[0], f0[1], H.u[0], L.u[0]);
    split2(f0[2], f0[3], H.u[1], L.u[1]);
    split2(f1[0], f1[1], H.u[2], L.u[2]);
    split2(f1[2], f1[3], H.u[3], L.u[3]);
    h = H.s; l = L.s;
}

// hi-only variant (4 perms, no lo)
__device__ __forceinline__ short8 hi8(f32x4 f0, f32x4 f1) {
    union { u32 u[4]; short8 s; } H;
    H.u[0] = __builtin_amdgcn_perm(__float_as_uint(f0[1]), __float_as_uint(f0[0]), 0x07060302u);
    H.u[1] = __builtin_amdgcn_perm(__float_as_uint(f0[3]), __float_as_uint(f0[2]), 0x07060302u);
    H.u[2] = __builtin_amdgcn_perm(__float_as_uint(f1[1]), __float_as_uint(f1[0]), 0x07060302u);
    H.u[3] = __builtin_amdgcn_perm(__float_as_uint(f1[3]), __float_as_uint(f1[2]), 0x07060302u);
    return H.s;
}

// Packed hi/lo layout for a logical [R x K] fp32 matrix (same byte count):
// per row, per 32-k chunk: 16 u32 of hi pairs (k ascending), then 16 u32 of lo.

// ---------------------------------------------------------------------------
// V [LK x DD] -> packed Vhl [LK x DD] and packed Vthl [DD x LK], per batch.
// ---------------------------------------------------------------------------
__global__ __launch_bounds__(256) void transpose_pack_v(const float* __restrict__ V,
                                                        float* __restrict__ Vhl,
                                                        float* __restrict__ Vthl) {
    __shared__ float tile[32][33];
    const int b = blockIdx.z;
    const int c0 = blockIdx.x * 32;   // d
    const int r0 = blockIdx.y * 32;   // kv
    const int t = threadIdx.x;
    const int r = t >> 3, c4 = (t & 7) * 4;
    const float* Vb = V + (size_t)b * LK * DD;
    f32x4 f = *(const f32x4*)(Vb + (size_t)(r0 + r) * DD + c0 + c4);

    u32 h0, l0, h1, l1;
    split2(f[0], f[1], h0, l0);
    split2(f[2], f[3], h1, l1);
    u32* vb = (u32*)Vhl + (size_t)b * LK * DD + (size_t)(r0 + r) * DD
            + (c0 >> 5) * 32 + (t & 7) * 2;
    *(u32x2*)vb        = u32x2{h0, h1};
    *(u32x2*)(vb + 16) = u32x2{l0, l1};

    tile[r][c4 + 0] = f[0]; tile[r][c4 + 1] = f[1];
    tile[r][c4 + 2] = f[2]; tile[r][c4 + 3] = f[3];
    __syncthreads();

    const int n = t >> 3, k4 = (t & 7) * 4;
    f32x4 o = {tile[k4 + 0][n], tile[k4 + 1][n], tile[k4 + 2][n], tile[k4 + 3][n]};
    split2(o[0], o[1], h0, l0);
    split2(o[2], o[3], h1, l1);
    u32* vtb = (u32*)Vthl + (size_t)b * DD * LK + (size_t)(c0 + n) * LK
             + (r0 >> 5) * 32 + (t & 7) * 2;
    *(u32x2*)vtb        = u32x2{h0, h1};
    *(u32x2*)(vtb + 16) = u32x2{l0, l1};
}

// ---------------------------------------------------------------------------
// 4-phase split-bf16 GEMM, v2 schedule (deep flight window, minimal barriers):
//   C[1024 x NG] = A[1024 x KG] * B[NG x KG]^T  per batch
// BM=256, BN in {256,128}. 8 waves (2M x 4N), double-buffered LDS.
// Per K-tile (BK=32 logical k = 128 B/row), 4 phases. Schedule:
//   qp0: issue ALL next-tile global_load_lds (deepest flight: ~3.5 phases),
//        read B frags (kept in regs all tile) + A frags
//   every qp: reads -> lgkmcnt(0) -> sched_barrier -> setprio(1) MFMA setprio(0)
//             -> [qp3 only: vmcnt(0)] -> s_barrier
// Correctness: intra-tile phases are read-after-read on stable buf p (no
// barrier needed between them for safety; trailing barrier is co-scheduling).
// Buf p^1 overwrite (issued qp0) is safe: its last reads ended before the
// previous tile-boundary barrier. vmcnt(0) at qp3 + barrier makes buf p^1
// LDS-visible to all waves before the next tile reads it. vmcnt never drains
// mid-tile; loads span the whole tile's compute.
//   APACKED=1: A pre-packed hi/lo. APACKED=0: A raw fp32, frags via perm.
//   NPROD=3: Ah*Bh+Ah*Bl+Al*Bh ; NPROD=2: Ah*Bh+Ah*Bl (P in [0,1]).
// LDS swizzle: rows of 8 x 16B chunks, phys chunk = logical ^ (row&7).
// XCD swizzle bijective (nwg == 256, % 8 == 0).
// ---------------------------------------------------------------------------
template <int KG, int NG, int BN, int NPROD, int APACKED>
__global__ __launch_bounds__(512, 2) void gemm4ph(const float* __restrict__ A,
                                                  const float* __restrict__ B,
                                                  float* __restrict__ C) {
    constexpr int BM   = 256;
    constexpr int NI   = 8;             // a-frags per wave (128 rows)
    constexpr int NJ   = BN / 64;       // b-frags per wave (BN/4 cols)
    constexpr int ARND = 4;             // A staging rounds (64 rows each)
    constexpr int BRND = BN / 64;       // B staging rounds (64 rows each)
    constexpr int NT   = KG / 32;       // K-tiles

    __shared__ float smA[2][BM * 32];
    __shared__ float smB[2][BN * 32];

    constexpr int GX = 1024 / BM, GYY = NG / BN;
    constexpr u32 nwg = (u32)(GX * GYY * BATCH);
    const u32 wgid = blockIdx.x + blockIdx.y * GX + blockIdx.z * (GX * GYY);
    const u32 swz  = (wgid & 7) * (nwg / 8) + (wgid >> 3);
    const int bm0  = (int)(swz % GX) * BM;
    const int bn0  = (int)((swz / GX) % GYY) * BN;
    const int b    = (int)(swz / (GX * GYY));

    const int tid = threadIdx.x;
    const int w = tid >> 6, lane = tid & 63;
    const int mf = lane & 15, q = lane >> 4, e = mf & 7;
    const int ch = ((q) ^ e) * 4;            // packed hi subchunk q
    const int cl = ((4 + q) ^ e) * 4;        // packed lo subchunk q
    const int c0 = ((2 * q) ^ e) * 4;        // raw fp32 logical chunk 2q
    const int c1 = ((2 * q + 1) ^ e) * 4;    // raw fp32 logical chunk 2q+1
    const int wmL = (w >> 2) * (BM / 2);     // wave row origin (2 M-waves)
    const int wnL = (w & 3) * (BN / 4);      // wave col origin (4 N-waves)

    // staging map: thread covers row (r*64 + tid>>3), phys chunk (tid&7)
    const int rowoff = tid >> 3;
    const int ckoff  = ((tid & 7) ^ ((tid >> 3) & 7)) * 4;   // logical chunk, u32
    const u32* Ag = (const u32*)A + (size_t)b * 1024 * KG + (size_t)(bm0 + rowoff) * KG + ckoff;
    const u32* Bg = (const u32*)B + (size_t)b * NG * KG   + (size_t)(bn0 + rowoff) * KG + ckoff;

    f32x4 acc[NI][NJ] = {};

    auto stageAll = [&](int pb, int kc) {
        const u32* ag = Ag + kc * 32;
        const u32* bg = Bg + kc * 32;
#pragma unroll
        for (int r = 0; r < BRND; ++r)
            __builtin_amdgcn_global_load_lds((const AS1 u32*)(bg + (size_t)r * 64 * KG),
                                             (AS3 u32*)(&smB[pb][(r * 512 + tid) * 4]), 16, 0, 0);
#pragma unroll
        for (int r = 0; r < ARND; ++r)
            __builtin_amdgcn_global_load_lds((const AS1 u32*)(ag + (size_t)r * 64 * KG),
                                             (AS3 u32*)(&smA[pb][(r * 512 + tid) * 4]), 16, 0, 0);
    };

    // prologue: full tile 0, drain once
    stageAll(0, 0);
    asm volatile("s_waitcnt vmcnt(0)" ::: "memory");
    __builtin_amdgcn_s_barrier();

    int p = 0;
    for (int kc = 0; kc < NT; ++kc) {
        const float* As = &smA[p][0];
        const float* Bs = &smB[p][0];
        short8 bh[NJ], bl[NJ];
#pragma unroll
        for (int qp = 0; qp < 4; ++qp) {
            if (qp == 0) {
                if (kc + 1 < NT) stageAll(p ^ 1, kc + 1);   // deepest flight window
#pragma unroll
                for (int j = 0; j < NJ; ++j) {
                    const int rb = (wnL + mf + j * 16) * 32;
                    bh[j] = *(const short8*)&Bs[rb + ch];
                    bl[j] = *(const short8*)&Bs[rb + cl];
                }
            }
            short8 a_h[2], a_l[2];
#pragma unroll
            for (int ii = 0; ii < 2; ++ii) {
                const int ra = (wmL + mf + (qp * 2 + ii) * 16) * 32;
                if constexpr (APACKED) {
                    a_h[ii] = *(const short8*)&As[ra + ch];
                    if constexpr (NPROD == 3) a_l[ii] = *(const short8*)&As[ra + cl];
                } else {
                    f32x4 f0 = *(const f32x4*)&As[ra + c0];
                    f32x4 f1 = *(const f32x4*)&As[ra + c1];
                    if constexpr (NPROD == 3) mk_frags(f0, f1, a_h[ii], a_l[ii]);
                    else                      a_h[ii] = hi8(f0, f1);
                }
            }
            asm volatile("s_waitcnt lgkmcnt(0)" ::: "memory");
            __builtin_amdgcn_sched_barrier(0);
            __builtin_amdgcn_s_setprio(1);
#pragma unroll
            for (int ii = 0; ii < 2; ++ii)
#pragma unroll
                for (int j = 0; j < NJ; ++j) {
                    const int i = qp * 2 + ii;
                    acc[i][j] = __builtin_amdgcn_mfma_f32_16x16x32_bf16(a_h[ii], bh[j], acc[i][j], 0, 0, 0);
                    acc[i][j] = __builtin_amdgcn_mfma_f32_16x16x32_bf16(a_h[ii], bl[j], acc[i][j], 0, 0, 0);
                    if constexpr (NPROD == 3)
                        acc[i][j] = __builtin_amdgcn_mfma_f32_16x16x32_bf16(a_l[ii], bh[j], acc[i][j], 0, 0, 0);
                }
            __builtin_amdgcn_s_setprio(0);
            if (qp == 3) asm volatile("s_waitcnt vmcnt(0)" ::: "memory");  // next tile landed
            __builtin_amdgcn_s_barrier();
        }
        p ^= 1;
    }

    // epilogue: C/D layout col = lane&15, row = q*4 + reg  [m89-verified]
    float* Cb = C + (size_t)b * 1024 * NG + (size_t)bm0 * NG + bn0;
#pragma unroll
    for (int i = 0; i < NI; ++i)
#pragma unroll
        for (int j = 0; j < NJ; ++j)
#pragma unroll
            for (int r = 0; r < 4; ++r)
                Cb[(size_t)(wmL + i * 16 + q * 4 + r) * NG + wnL + j * 16 + mf] = acc[i][j][r];
}

// ---------------------------------------------------------------------------
// Barrier-free row softmax in place: one wave per row, 4 rows/block.
// ---------------------------------------------------------------------------
__global__ __launch_bounds__(256) void softmax_rows2(float* __restrict__ S) {
    const int t = threadIdx.x;
    const int wave = t >> 6, lane = t & 63;
    const size_t row = (size_t)blockIdx.x * 4 + wave;
    float* p = S + row * LK;
    f32x4 v[4];
#pragma unroll
    for (int c = 0; c < 4; ++c)
        v[c] = *(const f32x4*)(p + lane * 4 + c * 256);
    float m = -1e30f;
#pragma unroll
    for (int c = 0; c < 4; ++c)
        m = fmaxf(m, fmaxf(fmaxf(v[c][0], v[c][1]), fmaxf(v[c][2], v[c][3])));
#pragma unroll
    for (int off = 1; off < 64; off <<= 1) m = fmaxf(m, __shfl_xor(m, off, 64));
    float s = 0.0f;
#pragma unroll
    for (int c = 0; c < 4; ++c) {
        v[c][0] = __expf(v[c][0] - m);
        v[c][1] = __expf(v[c][1] - m);
        v[c][2] = __expf(v[c][2] - m);
        v[c][3] = __expf(v[c][3] - m);
        s += (v[c][0] + v[c][1]) + (v[c][2] + v[c][3]);
    }
#pragma unroll
    for (int off = 1; off < 64; off <<= 1) s += __shfl_xor(s, off, 64);
    const float inv = 1.0f / s;
#pragma unroll
    for (int c = 0; c < 4; ++c) {
        v[c] = v[c] * inv;
        *(f32x4*)(p + lane * 4 + c * 256) = v[c];
    }
}

// ===========================================================================
// Fallback (tiny ws): plain fp32 tiled GEMMs + block softmax
// ===========================================================================
constexpr int BMf = 64, BNf = 64, BKf = 16, PADf = 4;

__global__ __launch_bounds__(256) void softmax_rows(float* __restrict__ S) {
    float* p = S + (size_t)blockIdx.x * LK;
    const int t = threadIdx.x;
    float4 v = *(float4*)(p + (t << 2));
    float m = fmaxf(fmaxf(v.x, v.y), fmaxf(v.z, v.w));
#pragma unroll
    for (int off = 1; off < 64; off <<= 1) m = fmaxf(m, __shfl_xor(m, off, 64));
    __shared__ float redm[4]; __shared__ float reds[4];
    const int wave = t >> 6, lane = t & 63;
    if (lane == 0) redm[wave] = m;
    __syncthreads();
    m = fmaxf(fmaxf(redm[0], redm[1]), fmaxf(redm[2], redm[3]));
    v.x = __expf(v.x - m); v.y = __expf(v.y - m);
    v.z = __expf(v.z - m); v.w = __expf(v.w - m);
    float s = (v.x + v.y) + (v.z + v.w);
#pragma unroll
    for (int off = 1; off < 64; off <<= 1) s += __shfl_xor(s, off, 64);
    if (lane == 0) reds[wave] = s;
    __syncthreads();
    s = (reds[0] + reds[1]) + (reds[2] + reds[3]);
    const float inv = 1.0f / s;
    v.x *= inv; v.y *= inv; v.z *= inv; v.w *= inv;
    *(float4*)(p + (t << 2)) = v;
}

__global__ __launch_bounds__(256) void gemm_qvt(const float* __restrict__ Q,
                                                const float* __restrict__ V,
                                                float* __restrict__ S) {
    __shared__ __align__(16) float sA[BKf][BMf + PADf];
    __shared__ __align__(16) float sB[BKf][BNf + PADf];
    const int b = blockIdx.z;
    const float* Qb = Q + (size_t)b * LQ * DD + (size_t)blockIdx.x * BMf * DD;
    const float* Vb = V + (size_t)b * LK * DD + (size_t)blockIdx.y * BNf * DD;
    float*       Sb = S + (size_t)b * LQ * LK;
    const int tid = threadIdx.x;
    const int tx = tid & 15, ty = tid >> 4;
    const int lr = tid >> 2, lc = (tid & 3) << 2;
    float acc[4][4] = {};
    for (int k0 = 0; k0 < DD; k0 += BKf) {
        float4 qa = *(const float4*)(Qb + (size_t)lr * DD + k0 + lc);
        float4 va = *(const float4*)(Vb + (size_t)lr * DD + k0 + lc);
        __syncthreads();
        sA[lc + 0][lr] = qa.x; sA[lc + 1][lr] = qa.y; sA[lc + 2][lr] = qa.z; sA[lc + 3][lr] = qa.w;
        sB[lc + 0][lr] = va.x; sB[lc + 1][lr] = va.y; sB[lc + 2][lr] = va.z; sB[lc + 3][lr] = va.w;
        __syncthreads();
#pragma unroll
        for (int k = 0; k < BKf; ++k) {
            float4 a4 = *(const float4*)&sA[k][ty << 2];
            float4 b4 = *(const float4*)&sB[k][tx << 2];
            float a[4] = {a4.x, a4.y, a4.z, a4.w};
            float bb[4] = {b4.x, b4.y, b4.z, b4.w};
#pragma unroll
            for (int i = 0; i < 4; ++i)
#pragma unroll
                for (int j = 0; j < 4; ++j) acc[i][j] = fmaf(a[i], bb[j], acc[i][j]);
        }
    }
    const int r0 = blockIdx.x * BMf + (ty << 2), c0 = blockIdx.y * BNf + (tx << 2);
#pragma unroll
    for (int i = 0; i < 4; ++i) {
        float4 o = {acc[i][0], acc[i][1], acc[i][2], acc[i][3]};
        *(float4*)(Sb + (size_t)(r0 + i) * LK + c0) = o;
    }
}

__global__ __launch_bounds__(256) void gemm_pv(const float* __restrict__ P,
                                               const float* __restrict__ V,
                                               float* __restrict__ C) {
    __shared__ __align__(16) float sA[BKf][BMf + PADf];
    __shared__ __align__(16) float sB[BKf][BNf + PADf];
    const int b = blockIdx.z;
    const float* Pb = P + (size_t)b * LQ * LK + (size_t)blockIdx.x * BMf * LK;
    const float* Vb = V + (size_t)b * LK * DD;
    float*       Cb = C + (size_t)b * LQ * DD;
    const int tid = threadIdx.x;
    const int tx = tid & 15, ty = tid >> 4;
    const int lr = tid >> 2, lc = (tid & 3) << 2;
    const int bkr = tid >> 4, bcg = (tid & 15) << 2;
    const int n0 = blockIdx.y * BNf;
    float acc[4][4] = {};
    for (int k0 = 0; k0 < LK; k0 += BKf) {
        float4 pa = *(const float4*)(Pb + (size_t)lr * LK + k0 + lc);
        float4 vb = *(const float4*)(Vb + (size_t)(k0 + bkr) * DD + n0 + bcg);
        __syncthreads();
        sA[lc + 0][lr] = pa.x; sA[lc + 1][lr] = pa.y; sA[lc + 2][lr] = pa.z; sA[lc + 3][lr] = pa.w;
        *(float4*)&sB[bkr][bcg] = vb;
        __syncthreads();
#pragma unroll
        for (int k = 0; k < BKf; ++k) {
            float4 a4 = *(const float4*)&sA[k][ty << 2];
            float4 b4 = *(const float4*)&sB[k][tx << 2];
            float a[4] = {a4.x, a4.y, a4.z, a4.w};
            float bb[4] = {b4.x, b4.y, b4.z, b4.w};
#pragma unroll
            for (int i = 0; i < 4; ++i)
#pragma unroll
                for (int j = 0; j < 4; ++j) acc[i][j] = fmaf(a[i], bb[j], acc[i][j]);
        }
    }
    const int r0 = blockIdx.x * BMf + (ty << 2), c0 = n0 + (tx << 2);
#pragma unroll
    for (int i = 0; i < 4; ++i) {
        float4 o = {acc[i][0], acc[i][1], acc[i][2], acc[i][3]};
        *(float4*)(Cb + (size_t)(r0 + i) * DD + c0) = o;
    }
}

// ---------------------------------------------------------------------------
extern "C" void kernel_launch(void* const* d_in, const int* in_sizes, int n_in,
                              void* d_out, int out_size, void* d_ws, size_t ws_size,
                              hipStream_t stream) {
    const float* Q = (const float*)d_in[0];
    const float* V = (const float*)d_in[1];

    float* ctx  = (float*)d_out;                       // [16,1024,512]
    float* attn = ctx + (size_t)BATCH * LQ * DD;       // [16,1024,1024]

    const size_t qv_elems = (size_t)BATCH * LQ * DD;   // 8.4M floats = 33.55 MB
    const size_t need = 2 * qv_elems * sizeof(float);  // Vhl + Vthl = 67.1 MB

    if (ws_size >= need) {
        float* Vhl  = (float*)d_ws;
        float* Vthl = Vhl + qv_elems;
        transpose_pack_v<<<dim3(DD / 32, LK / 32, BATCH), 256, 0, stream>>>(V, Vhl, Vthl);
        // S = Q @ V^T : 256x256, A = Q raw fp32 (split in-kernel), B = Vhl
        gemm4ph<DD, LK, 256, 3, 0><<<dim3(4, 4, BATCH), 512, 0, stream>>>(Q, Vhl, attn);
        softmax_rows2<<<dim3(BATCH * LQ / 4), 256, 0, stream>>>(attn);
        // ctx = P @ V : 256x128, A = attn raw fp32 (hi in-kernel), B = Vthl
        gemm4ph<LK, DD, 128, 2, 0><<<dim3(4, 4, BATCH), 512, 0, stream>>>(attn, Vthl, ctx);
    } else {
        gemm_qvt<<<dim3(LQ / BMf, LK / BNf, BATCH), 256, 0, stream>>>(Q, V, attn);
        softmax_rows<<<dim3(BATCH * LQ), 256, 0, stream>>>(attn);
        gemm_pv<<<dim3(LQ / BMf, DD / BNf, BATCH), 256, 0, stream>>>(attn, V, ctx);
    }
}

// Round 8
// 276.587 us; speedup vs baseline: 1.0481x; 1.0481x over previous
//
#include <hip/hip_runtime.h>

#define BATCH 16
#define LQ    1024
#define LK    1024
#define DD    512

typedef unsigned int u32;
typedef short short8 __attribute__((ext_vector_type(8)));
typedef float f32x4 __attribute__((ext_vector_type(4)));
typedef u32 u32x2 __attribute__((ext_vector_type(2)));
#define AS1 __attribute__((address_space(1)))
#define AS3 __attribute__((address_space(3)))

// ---------------------------------------------------------------------------
// split fp32 pair -> packed bf16 hi (truncation) and bf16 lo (= x - hi)
// ---------------------------------------------------------------------------
__device__ __forceinline__ void split2(float x0, float x1, u32& hp, u32& lp) {
    u32 u0 = __float_as_uint(x0), u1 = __float_as_uint(x1);
    hp = __builtin_amdgcn_perm(u1, u0, 0x07060302u);   // (bf16(x0), bf16(x1))
    float l0 = x0 - __uint_as_float(u0 & 0xffff0000u);
    float l1 = x1 - __uint_as_float(u1 & 0xffff0000u);
    lp = __builtin_amdgcn_perm(__float_as_uint(l1), __float_as_uint(l0), 0x07060302u);
}

__device__ __forceinline__ void mk_frags(f32x4 f0, f32x4 f1, short8& h, short8& l) {
    union { u32 u[4]; short8 s; } H, L;
    split2(f0[0], f0[1], H.u[0], L.u[0]);
    split2(f0[2], f0[3], H.u[1], L.u[1]);
    split2(f1[0], f1[1], H.u[2], L.u[2]);
    split2(f1[2], f1[3], H.u[3], L.u[3]);
    h = H.s; l = L.s;
}

// hi-only variant (4 perms, no lo)
__device__ __forceinline__ short8 hi8(f32x4 f0, f32x4 f1) {
    union { u32 u[4]; short8 s; } H;
    H.u[0] = __builtin_amdgcn_perm(__float_as_uint(f0[1]), __float_as_uint(f0[0]), 0x07060302u);
    H.u[1] = __builtin_amdgcn_perm(__float_as_uint(f0[3]), __float_as_uint(f0[2]), 0x07060302u);
    H.u[2] = __builtin_amdgcn_perm(__float_as_uint(f1[1]), __float_as_uint(f1[0]), 0x07060302u);
    H.u[3] = __builtin_amdgcn_perm(__float_as_uint(f1[3]), __float_as_uint(f1[2]), 0x07060302u);
    return H.s;
}

// Packed hi/lo layout for a logical [R x K] fp32 matrix (same byte count):
// per row, per 32-k chunk: 16 u32 of hi pairs (k ascending), then 16 u32 of lo.

// ---------------------------------------------------------------------------
// V [LK x DD] -> packed Vhl [LK x DD] and packed Vthl [DD x LK], per batch.
// ---------------------------------------------------------------------------
__global__ __launch_bounds__(256) void transpose_pack_v(const float* __restrict__ V,
                                                        float* __restrict__ Vhl,
                                                        float* __restrict__ Vthl) {
    __shared__ float tile[32][33];
    const int b = blockIdx.z;
    const int c0 = blockIdx.x * 32;   // d
    const int r0 = blockIdx.y * 32;   // kv
    const int t = threadIdx.x;
    const int r = t >> 3, c4 = (t & 7) * 4;
    const float* Vb = V + (size_t)b * LK * DD;
    f32x4 f = *(const f32x4*)(Vb + (size_t)(r0 + r) * DD + c0 + c4);

    u32 h0, l0, h1, l1;
    split2(f[0], f[1], h0, l0);
    split2(f[2], f[3], h1, l1);
    u32* vb = (u32*)Vhl + (size_t)b * LK * DD + (size_t)(r0 + r) * DD
            + (c0 >> 5) * 32 + (t & 7) * 2;
    *(u32x2*)vb        = u32x2{h0, h1};
    *(u32x2*)(vb + 16) = u32x2{l0, l1};

    tile[r][c4 + 0] = f[0]; tile[r][c4 + 1] = f[1];
    tile[r][c4 + 2] = f[2]; tile[r][c4 + 3] = f[3];
    __syncthreads();

    const int n = t >> 3, k4 = (t & 7) * 4;
    f32x4 o = {tile[k4 + 0][n], tile[k4 + 1][n], tile[k4 + 2][n], tile[k4 + 3][n]};
    split2(o[0], o[1], h0, l0);
    split2(o[2], o[3], h1, l1);
    u32* vtb = (u32*)Vthl + (size_t)b * DD * LK + (size_t)(c0 + n) * LK
             + (r0 >> 5) * 32 + (t & 7) * 2;
    *(u32x2*)vtb        = u32x2{h0, h1};
    *(u32x2*)(vtb + 16) = u32x2{l0, l1};
}

// ---------------------------------------------------------------------------
// 4-phase counted-vmcnt split-bf16 GEMM, v3: r6's measured schedule (spread
// staging + counted waits + 2 barriers/phase) with A = RAW fp32 and the split
// VALU software-pipelined one phase ahead INSIDE the MFMA region (VALU||MFMA
// co-issue, m114) so no pack_q is needed and no split sits on the critical
// path.   C[1024 x NG] = A[1024 x KG] * B[NG x KG]^T  per batch.
// BM=256, BN in {256,128}. 8 waves (2M x 4N), double-buffered LDS.
//
// A-round consumption: wave-group 0 (rows 0-127) phases 0,1 read round A0,
// phases 2,3 read A1; group 1 (rows 128-255) reads A2 then A3.
// Staging spread: qp0 -> B01(kc+1); qp1 -> B23 (BN=256); qp2 -> A0,A2;
// qp3 -> A1,A3.  Per-tile outstanding-load bookkeeping (program order):
//   tile start: outstanding = A13(kc) [2]
//   qp0 issues B01 -> 4;  qp0-end vmcnt(2) => A13(kc) landed (needed by the
//       phase-1 region's prefetch of phase-2 rows).  Last tile: vmcnt(0).
//   qp1/qp2 issue B23 / A02 -> no waits.
//   qp3 issues A13(kc+1);  qp3-end vmcnt(2) => B(kc+1) + A02(kc+1) landed
//       (needed by next tile-start B-frag reads + phase-0 raw reads);
//       A13(kc+1) stays in flight (~1.5 phases) -> invariant restored.
// vmcnt(0) appears only in the prologue and last-tile qp0.
// Region content (phase qp): MFMA(a_cur) + {ds_read raw rows of qp+1 from the
// STABLE buf p + convert -> a_next}  (compiler interleaves; reads are
// compiler-visible so dependences are tracked).
// LDS swizzle: rows of 8 x 16B chunks, phys chunk = logical ^ (row&7).
// XCD swizzle bijective (nwg == 256, % 8 == 0). Epilogue layout m89-verified.
// ---------------------------------------------------------------------------
template <int KG, int NG, int BN, int NPROD>
__global__ __launch_bounds__(512, 2) void gemm4ph(const float* __restrict__ A,
                                                  const float* __restrict__ B,
                                                  float* __restrict__ C) {
    constexpr int BM   = 256;
    constexpr int NI   = 8;             // a-frags per wave (128 rows)
    constexpr int NJ   = BN / 64;       // b-frags per wave
    constexpr int BRND = BN / 64;       // B staging rounds (64 rows each)
    constexpr int NT   = KG / 32;       // K-tiles

    __shared__ float smA[2][BM * 32];
    __shared__ float smB[2][BN * 32];

    constexpr int GX = 1024 / BM, GYY = NG / BN;
    constexpr u32 nwg = (u32)(GX * GYY * BATCH);
    const u32 wgid = blockIdx.x + blockIdx.y * GX + blockIdx.z * (GX * GYY);
    const u32 swz  = (wgid & 7) * (nwg / 8) + (wgid >> 3);
    const int bm0  = (int)(swz % GX) * BM;
    const int bn0  = (int)((swz / GX) % GYY) * BN;
    const int b    = (int)(swz / (GX * GYY));

    const int tid = threadIdx.x;
    const int w = tid >> 6, lane = tid & 63;
    const int mf = lane & 15, q = lane >> 4, e = mf & 7;
    const int ch = ((q) ^ e) * 4;            // packed hi subchunk q (B)
    const int cl = ((4 + q) ^ e) * 4;        // packed lo subchunk q (B)
    const int c0 = ((2 * q) ^ e) * 4;        // raw fp32 logical chunk 2q (A)
    const int c1 = ((2 * q + 1) ^ e) * 4;    // raw fp32 logical chunk 2q+1 (A)
    const int wmL = (w >> 2) * (BM / 2);     // wave row origin (2 M-waves)
    const int wnL = (w & 3) * (BN / 4);      // wave col origin (4 N-waves)

    // staging map: thread covers row (r*64 + tid>>3), phys chunk (tid&7)
    const int rowoff = tid >> 3;
    const int ckoff  = ((tid & 7) ^ ((tid >> 3) & 7)) * 4;   // logical chunk, u32
    const u32* Ag = (const u32*)A + (size_t)b * 1024 * KG + (size_t)(bm0 + rowoff) * KG + ckoff;
    const u32* Bg = (const u32*)B + (size_t)b * NG * KG   + (size_t)(bn0 + rowoff) * KG + ckoff;

    f32x4 acc[NI][NJ] = {};

    auto issueB2 = [&](int pb, int kc, int r0) {
        const u32* bg = Bg + kc * 32;
#pragma unroll
        for (int r = 0; r < 2; ++r)
            __builtin_amdgcn_global_load_lds((const AS1 u32*)(bg + (size_t)(r0 + r) * 64 * KG),
                                             (AS3 u32*)(&smB[pb][((r0 + r) * 512 + tid) * 4]), 16, 0, 0);
    };
    auto issueA2 = [&](int pb, int kc, int ra, int rb) {
        const u32* ag = Ag + kc * 32;
        __builtin_amdgcn_global_load_lds((const AS1 u32*)(ag + (size_t)ra * 64 * KG),
                                         (AS3 u32*)(&smA[pb][(ra * 512 + tid) * 4]), 16, 0, 0);
        __builtin_amdgcn_global_load_lds((const AS1 u32*)(ag + (size_t)rb * 64 * KG),
                                         (AS3 u32*)(&smA[pb][(rb * 512 + tid) * 4]), 16, 0, 0);
    };

    // prologue: full tile 0, drain once
    issueB2(0, 0, 0);
    if constexpr (BRND == 4) issueB2(0, 0, 2);
    issueA2(0, 0, 0, 2);
    issueA2(0, 0, 1, 3);
    asm volatile("s_waitcnt vmcnt(0)" ::: "memory");
    __builtin_amdgcn_s_barrier();

    int p = 0;
    for (int kc = 0; kc < NT; ++kc) {
        const bool more = (kc + 1 < NT);
        const float* As = &smA[p][0];
        const float* Bs = &smB[p][0];

        // ---- tile-start reads: B frags (whole tile) + phase-0 A raw+convert
        short8 bh[NJ], bl[NJ];
#pragma unroll
        for (int j = 0; j < NJ; ++j) {
            const int rb = (wnL + mf + j * 16) * 32;
            bh[j] = *(const short8*)&Bs[rb + ch];
            bl[j] = *(const short8*)&Bs[rb + cl];
        }
        short8 ah[2], al[2], nh[2], nl[2];
#pragma unroll
        for (int ii = 0; ii < 2; ++ii) {
            const int ra = (wmL + mf + ii * 16) * 32;
            f32x4 f0 = *(const f32x4*)&As[ra + c0];
            f32x4 f1 = *(const f32x4*)&As[ra + c1];
            if constexpr (NPROD == 3) mk_frags(f0, f1, ah[ii], al[ii]);
            else                      ah[ii] = hi8(f0, f1);
        }

#pragma unroll
        for (int qp = 0; qp < 4; ++qp) {
            // ---- spread staging issues (before lead barrier) ----
            if (more) {
                if (qp == 0) issueB2(p ^ 1, kc + 1, 0);
                if (qp == 1) { if constexpr (BRND == 4) issueB2(p ^ 1, kc + 1, 2); }
                if (qp == 2) issueA2(p ^ 1, kc + 1, 0, 2);
                if (qp == 3) issueA2(p ^ 1, kc + 1, 1, 3);
            }
            __builtin_amdgcn_s_barrier();
            asm volatile("s_waitcnt lgkmcnt(0)" ::: "memory");
            __builtin_amdgcn_sched_barrier(0);
            __builtin_amdgcn_s_setprio(1);
#pragma unroll
            for (int ii = 0; ii < 2; ++ii)
#pragma unroll
                for (int j = 0; j < NJ; ++j) {
                    const int i = qp * 2 + ii;
                    acc[i][j] = __builtin_amdgcn_mfma_f32_16x16x32_bf16(ah[ii], bh[j], acc[i][j], 0, 0, 0);
                    acc[i][j] = __builtin_amdgcn_mfma_f32_16x16x32_bf16(ah[ii], bl[j], acc[i][j], 0, 0, 0);
                    if constexpr (NPROD == 3)
                        acc[i][j] = __builtin_amdgcn_mfma_f32_16x16x32_bf16(al[ii], bh[j], acc[i][j], 0, 0, 0);
                }
            // prefetch next phase's raw A + convert, overlapped with the MFMAs
            if (qp < 3) {
#pragma unroll
                for (int ii = 0; ii < 2; ++ii) {
                    const int ra = (wmL + mf + ((qp + 1) * 2 + ii) * 16) * 32;
                    f32x4 f0 = *(const f32x4*)&As[ra + c0];
                    f32x4 f1 = *(const f32x4*)&As[ra + c1];
                    if constexpr (NPROD == 3) mk_frags(f0, f1, nh[ii], nl[ii]);
                    else                      nh[ii] = hi8(f0, f1);
                }
            }
            __builtin_amdgcn_s_setprio(0);
            // ---- counted waits (before trailing barrier) ----
            if (qp == 0) {
                if (more) asm volatile("s_waitcnt vmcnt(2)" ::: "memory");
                else      asm volatile("s_waitcnt vmcnt(0)" ::: "memory");
            }
            if (qp == 3 && more) asm volatile("s_waitcnt vmcnt(2)" ::: "memory");
            __builtin_amdgcn_s_barrier();
            if (qp < 3) {
                ah[0] = nh[0]; ah[1] = nh[1];
                if constexpr (NPROD == 3) { al[0] = nl[0]; al[1] = nl[1]; }
            }
        }
        p ^= 1;
    }

    // epilogue: C/D layout col = lane&15, row = q*4 + reg  [m89-verified]
    float* Cb = C + (size_t)b * 1024 * NG + (size_t)bm0 * NG + bn0;
#pragma unroll
    for (int i = 0; i < NI; ++i)
#pragma unroll
        for (int j = 0; j < NJ; ++j)
#pragma unroll
            for (int r = 0; r < 4; ++r)
                Cb[(size_t)(wmL + i * 16 + q * 4 + r) * NG + wnL + j * 16 + mf] = acc[i][j][r];
}

// ---------------------------------------------------------------------------
// Barrier-free row softmax in place: one wave per row, 4 rows/block.
// ---------------------------------------------------------------------------
__global__ __launch_bounds__(256) void softmax_rows2(float* __restrict__ S) {
    const int t = threadIdx.x;
    const int wave = t >> 6, lane = t & 63;
    const size_t row = (size_t)blockIdx.x * 4 + wave;
    float* p = S + row * LK;
    f32x4 v[4];
#pragma unroll
    for (int c = 0; c < 4; ++c)
        v[c] = *(const f32x4*)(p + lane * 4 + c * 256);
    float m = -1e30f;
#pragma unroll
    for (int c = 0; c < 4; ++c)
        m = fmaxf(m, fmaxf(fmaxf(v[c][0], v[c][1]), fmaxf(v[c][2], v[c][3])));
#pragma unroll
    for (int off = 1; off < 64; off <<= 1) m = fmaxf(m, __shfl_xor(m, off, 64));
    float s = 0.0f;
#pragma unroll
    for (int c = 0; c < 4; ++c) {
        v[c][0] = __expf(v[c][0] - m);
        v[c][1] = __expf(v[c][1] - m);
        v[c][2] = __expf(v[c][2] - m);
        v[c][3] = __expf(v[c][3] - m);
        s += (v[c][0] + v[c][1]) + (v[c][2] + v[c][3]);
    }
#pragma unroll
    for (int off = 1; off < 64; off <<= 1) s += __shfl_xor(s, off, 64);
    const float inv = 1.0f / s;
#pragma unroll
    for (int c = 0; c < 4; ++c) {
        v[c] = v[c] * inv;
        *(f32x4*)(p + lane * 4 + c * 256) = v[c];
    }
}

// ===========================================================================
// Fallback (tiny ws): plain fp32 tiled GEMMs + block softmax
// ===========================================================================
constexpr int BMf = 64, BNf = 64, BKf = 16, PADf = 4;

__global__ __launch_bounds__(256) void softmax_rows(float* __restrict__ S) {
    float* p = S + (size_t)blockIdx.x * LK;
    const int t = threadIdx.x;
    float4 v = *(float4*)(p + (t << 2));
    float m = fmaxf(fmaxf(v.x, v.y), fmaxf(v.z, v.w));
#pragma unroll
    for (int off = 1; off < 64; off <<= 1) m = fmaxf(m, __shfl_xor(m, off, 64));
    __shared__ float redm[4]; __shared__ float reds[4];
    const int wave = t >> 6, lane = t & 63;
    if (lane == 0) redm[wave] = m;
    __syncthreads();
    m = fmaxf(fmaxf(redm[0], redm[1]), fmaxf(redm[2], redm[3]));
    v.x = __expf(v.x - m); v.y = __expf(v.y - m);
    v.z = __expf(v.z - m); v.w = __expf(v.w - m);
    float s = (v.x + v.y) + (v.z + v.w);
#pragma unroll
    for (int off = 1; off < 64; off <<= 1) s += __shfl_xor(s, off, 64);
    if (lane == 0) reds[wave] = s;
    __syncthreads();
    s = (reds[0] + reds[1]) + (reds[2] + reds[3]);
    const float inv = 1.0f / s;
    v.x *= inv; v.y *= inv; v.z *= inv; v.w *= inv;
    *(float4*)(p + (t << 2)) = v;
}

__global__ __launch_bounds__(256) void gemm_qvt(const float* __restrict__ Q,
                                                const float* __restrict__ V,
                                                float* __restrict__ S) {
    __shared__ __align__(16) float sA[BKf][BMf + PADf];
    __shared__ __align__(16) float sB[BKf][BNf + PADf];
    const int b = blockIdx.z;
    const float* Qb = Q + (size_t)b * LQ * DD + (size_t)blockIdx.x * BMf * DD;
    const float* Vb = V + (size_t)b * LK * DD + (size_t)blockIdx.y * BNf * DD;
    float*       Sb = S + (size_t)b * LQ * LK;
    const int tid = threadIdx.x;
    const int tx = tid & 15, ty = tid >> 4;
    const int lr = tid >> 2, lc = (tid & 3) << 2;
    float acc[4][4] = {};
    for (int k0 = 0; k0 < DD; k0 += BKf) {
        float4 qa = *(const float4*)(Qb + (size_t)lr * DD + k0 + lc);
        float4 va = *(const float4*)(Vb + (size_t)lr * DD + k0 + lc);
        __syncthreads();
        sA[lc + 0][lr] = qa.x; sA[lc + 1][lr] = qa.y; sA[lc + 2][lr] = qa.z; sA[lc + 3][lr] = qa.w;
        sB[lc + 0][lr] = va.x; sB[lc + 1][lr] = va.y; sB[lc + 2][lr] = va.z; sB[lc + 3][lr] = va.w;
        __syncthreads();
#pragma unroll
        for (int k = 0; k < BKf; ++k) {
            float4 a4 = *(const float4*)&sA[k][ty << 2];
            float4 b4 = *(const float4*)&sB[k][tx << 2];
            float a[4] = {a4.x, a4.y, a4.z, a4.w};
            float bb[4] = {b4.x, b4.y, b4.z, b4.w};
#pragma unroll
            for (int i = 0; i < 4; ++i)
#pragma unroll
                for (int j = 0; j < 4; ++j) acc[i][j] = fmaf(a[i], bb[j], acc[i][j]);
        }
    }
    const int r0 = blockIdx.x * BMf + (ty << 2), c0 = blockIdx.y * BNf + (tx << 2);
#pragma unroll
    for (int i = 0; i < 4; ++i) {
        float4 o = {acc[i][0], acc[i][1], acc[i][2], acc[i][3]};
        *(float4*)(Sb + (size_t)(r0 + i) * LK + c0) = o;
    }
}

__global__ __launch_bounds__(256) void gemm_pv(const float* __restrict__ P,
                                               const float* __restrict__ V,
                                               float* __restrict__ C) {
    __shared__ __align__(16) float sA[BKf][BMf + PADf];
    __shared__ __align__(16) float sB[BKf][BNf + PADf];
    const int b = blockIdx.z;
    const float* Pb = P + (size_t)b * LQ * LK + (size_t)blockIdx.x * BMf * LK;
    const float* Vb = V + (size_t)b * LK * DD;
    float*       Cb = C + (size_t)b * LQ * DD;
    const int tid = threadIdx.x;
    const int tx = tid & 15, ty = tid >> 4;
    const int lr = tid >> 2, lc = (tid & 3) << 2;
    const int bkr = tid >> 4, bcg = (tid & 15) << 2;
    const int n0 = blockIdx.y * BNf;
    float acc[4][4] = {};
    for (int k0 = 0; k0 < LK; k0 += BKf) {
        float4 pa = *(const float4*)(Pb + (size_t)lr * LK + k0 + lc);
        float4 vb = *(const float4*)(Vb + (size_t)(k0 + bkr) * DD + n0 + bcg);
        __syncthreads();
        sA[lc + 0][lr] = pa.x; sA[lc + 1][lr] = pa.y; sA[lc + 2][lr] = pa.z; sA[lc + 3][lr] = pa.w;
        *(float4*)&sB[bkr][bcg] = vb;
        __syncthreads();
#pragma unroll
        for (int k = 0; k < BKf; ++k) {
            float4 a4 = *(const float4*)&sA[k][ty << 2];
            float4 b4 = *(const float4*)&sB[k][tx << 2];
            float a[4] = {a4.x, a4.y, a4.z, a4.w};
            float bb[4] = {b4.x, b4.y, b4.z, b4.w};
#pragma unroll
            for (int i = 0; i < 4; ++i)
#pragma unroll
                for (int j = 0; j < 4; ++j) acc[i][j] = fmaf(a[i], bb[j], acc[i][j]);
        }
    }
    const int r0 = blockIdx.x * BMf + (ty << 2), c0 = n0 + (tx << 2);
#pragma unroll
    for (int i = 0; i < 4; ++i) {
        float4 o = {acc[i][0], acc[i][1], acc[i][2], acc[i][3]};
        *(float4*)(Cb + (size_t)(r0 + i) * DD + c0) = o;
    }
}

// ---------------------------------------------------------------------------
extern "C" void kernel_launch(void* const* d_in, const int* in_sizes, int n_in,
                              void* d_out, int out_size, void* d_ws, size_t ws_size,
                              hipStream_t stream) {
    const float* Q = (const float*)d_in[0];
    const float* V = (const float*)d_in[1];

    float* ctx  = (float*)d_out;                       // [16,1024,512]
    float* attn = ctx + (size_t)BATCH * LQ * DD;       // [16,1024,1024]

    const size_t qv_elems = (size_t)BATCH * LQ * DD;   // 8.4M floats = 33.55 MB
    const size_t need = 2 * qv_elems * sizeof(float);  // Vhl + Vthl = 67.1 MB

    if (ws_size >= need) {
        float* Vhl  = (float*)d_ws;
        float* Vthl = Vhl + qv_elems;
        transpose_pack_v<<<dim3(DD / 32, LK / 32, BATCH), 256, 0, stream>>>(V, Vhl, Vthl);
        // S = Q @ V^T : 256x256, A = Q raw fp32 (split pipelined in-region)
        gemm4ph<DD, LK, 256, 3><<<dim3(4, 4, BATCH), 512, 0, stream>>>(Q, Vhl, attn);
        softmax_rows2<<<dim3(BATCH * LQ / 4), 256, 0, stream>>>(attn);
        // ctx = P @ V : 256x128, A = attn raw fp32 (hi8 pipelined in-region)
        gemm4ph<LK, DD, 128, 2><<<dim3(4, 4, BATCH), 512, 0, stream>>>(attn, Vthl, ctx);
    } else {
        gemm_qvt<<<dim3(LQ / BMf, LK / BNf, BATCH), 256, 0, stream>>>(Q, V, attn);
        softmax_rows<<<dim3(BATCH * LQ), 256, 0, stream>>>(attn);
        gemm_pv<<<dim3(LQ / BMf, DD / BNf, BATCH), 256, 0, stream>>>(attn, V, ctx);
    }
}